// Round 1
// baseline (198.245 us; speedup 1.0000x reference)
//
#include <hip/hip_runtime.h>
#include <hip/hip_bf16.h>
#include <stdint.h>

typedef __hip_bfloat16 bf16;
typedef __attribute__((ext_vector_type(8))) short short8;
typedef __attribute__((ext_vector_type(4))) short short4v;
typedef __attribute__((ext_vector_type(4))) float f32x4;

#define AS1 __attribute__((address_space(1)))
#define AS3 __attribute__((address_space(3)))

static constexpr int SEQ = 2048, DM = 1024, DHD = 64;
static constexpr int MROWS = 2 * SEQ;  // 4096

__device__ __forceinline__ short f2b(float f) {
  __hip_bfloat16 h = __float2bfloat16(f);
  return *reinterpret_cast<short*>(&h);
}

// ---------------- prep: x -> bf16, x+pos -> bf16 ----------------
__global__ __launch_bounds__(256) void prep_inputs(const float* __restrict__ x,
                                                   const float* __restrict__ pos,
                                                   bf16* __restrict__ xb,
                                                   bf16* __restrict__ aib) {
  int i = blockIdx.x * 256 + threadIdx.x;
  const int n4 = MROWS * DM / 4;
  if (i >= n4) return;
  f32x4 xv = ((const f32x4*)x)[i];
  f32x4 pv = ((const f32x4*)pos)[i];
  short4v xo, ao;
#pragma unroll
  for (int j = 0; j < 4; ++j) {
    xo[j] = f2b(xv[j]);
    ao[j] = f2b(xv[j] + pv[j]);
  }
  ((short4v*)xb)[i] = xo;
  ((short4v*)aib)[i] = ao;
}

// ---------------- weight transpose: [R][C] f32 -> [C][R] bf16 (per z-slice) --
__global__ __launch_bounds__(256) void transpose_w(const float* __restrict__ in,
                                                   bf16* __restrict__ out, int R, int C) {
  __shared__ float t[64][65];
  int ct = blockIdx.x, rt = blockIdx.y, z = blockIdx.z;
  in += (size_t)z * R * C;
  out += (size_t)z * R * C;
  int c = threadIdx.x & 63, g = threadIdx.x >> 6;
#pragma unroll
  for (int j = 0; j < 16; ++j) {
    int r = g * 16 + j;
    t[r][c] = in[(size_t)(rt * 64 + r) * C + (ct * 64 + c)];
  }
  __syncthreads();
#pragma unroll
  for (int j = 0; j < 16; ++j) {
    int rr = g * 16 + j;
    out[(size_t)(ct * 64 + rr) * R + (rt * 64 + c)] = __float2bfloat16(t[c][rr]);
  }
}

// ---------------- 128x128 GEMM body (A[M][1024] bf16, Bt[N][1024] bf16) -----
template <typename OutT>
__device__ __forceinline__ void gemm128_body(const bf16* __restrict__ A,
                                             const bf16* __restrict__ Bt,
                                             const float* __restrict__ bias,
                                             OutT* __restrict__ C, int mt, int nt) {
  __shared__ alignas(16) bf16 Al[128 * 32];
  __shared__ alignas(16) bf16 Bl[128 * 32];
  const int lane = threadIdx.x & 63, wv = threadIdx.x >> 6;
  const int wr = wv >> 1, wc = wv & 1;
  const bf16* Ab = A + (size_t)mt * 128 * DM;
  const bf16* Bb = Bt + (size_t)nt * 128 * DM;

  f32x4 acc[4][4];
#pragma unroll
  for (int i = 0; i < 4; ++i)
#pragma unroll
    for (int j = 0; j < 4; ++j) acc[i][j] = (f32x4){0.f, 0.f, 0.f, 0.f};

  for (int kt = 0; kt < DM / 32; ++kt) {
    int k0 = kt * 32;
#pragma unroll
    for (int c = 0; c < 2; ++c) {
      int li0 = wv * 64 + c * 256;
      int li = li0 + lane;
      int row = li >> 2, sl = li & 3;
      int gs = sl ^ ((row >> 1) & 3);
      __builtin_amdgcn_global_load_lds((const AS1 void*)(Ab + (size_t)row * DM + k0 + gs * 8),
                                       (AS3 void*)(&Al[li0 * 8]), 16, 0, 0);
    }
#pragma unroll
    for (int c = 0; c < 2; ++c) {
      int li0 = wv * 64 + c * 256;
      int li = li0 + lane;
      int row = li >> 2, sl = li & 3;
      int gs = sl ^ ((row >> 1) & 3);
      __builtin_amdgcn_global_load_lds((const AS1 void*)(Bb + (size_t)row * DM + k0 + gs * 8),
                                       (AS3 void*)(&Bl[li0 * 8]), 16, 0, 0);
    }
    __syncthreads();

    short8 af[4], bfr[4];
    const int kb = lane >> 4;
#pragma unroll
    for (int mi = 0; mi < 4; ++mi) {
      int r = wr * 64 + mi * 16 + (lane & 15);
      af[mi] = *(const short8*)(&Al[r * 32 + ((kb ^ ((r >> 1) & 3)) << 3)]);
    }
#pragma unroll
    for (int ni = 0; ni < 4; ++ni) {
      int r = wc * 64 + ni * 16 + (lane & 15);
      bfr[ni] = *(const short8*)(&Bl[r * 32 + ((kb ^ ((r >> 1) & 3)) << 3)]);
    }
#pragma unroll
    for (int mi = 0; mi < 4; ++mi)
#pragma unroll
      for (int ni = 0; ni < 4; ++ni)
        acc[mi][ni] = __builtin_amdgcn_mfma_f32_16x16x32_bf16(af[mi], bfr[ni], acc[mi][ni], 0, 0, 0);
    __syncthreads();
  }

#pragma unroll
  for (int mi = 0; mi < 4; ++mi) {
#pragma unroll
    for (int ni = 0; ni < 4; ++ni) {
      int col = nt * 128 + wc * 64 + ni * 16 + (lane & 15);
      float bv = bias[col];
#pragma unroll
      for (int j = 0; j < 4; ++j) {
        int row = mt * 128 + wr * 64 + mi * 16 + (lane >> 4) * 4 + j;
        float v = acc[mi][ni][j] + bv;
        if constexpr (__hip_internal::is_same<OutT, bf16>::value) {
          C[(size_t)row * DM + col] = __float2bfloat16(v);
        } else {
          C[(size_t)row * DM + col] = v;
        }
      }
    }
  }
}

__global__ __launch_bounds__(256) void qkv_gemm(const bf16* __restrict__ aib,
                                                const bf16* __restrict__ xb,
                                                const bf16* __restrict__ wqt,
                                                const bf16* __restrict__ wkt,
                                                const bf16* __restrict__ wvt,
                                                const float* __restrict__ bq,
                                                const float* __restrict__ bk,
                                                const float* __restrict__ bv,
                                                bf16* __restrict__ Q, bf16* __restrict__ K,
                                                bf16* __restrict__ V) {
  int mt = blockIdx.x & 31;
  int nt = (blockIdx.x >> 5) & 7;
  int mat = blockIdx.x >> 8;
  const bf16* A = (mat == 2) ? xb : aib;
  const bf16* Bt = (mat == 0) ? wqt : (mat == 1) ? wkt : wvt;
  const float* bias = (mat == 0) ? bq : (mat == 1) ? bk : bv;
  bf16* C = (mat == 0) ? Q : (mat == 1) ? K : V;
  gemm128_body<bf16>(A, Bt, bias, C, mt, nt);
}

__global__ __launch_bounds__(256) void o_gemm(const bf16* __restrict__ Z,
                                              const bf16* __restrict__ wot,
                                              const float* __restrict__ bo,
                                              float* __restrict__ out) {
  int mt = blockIdx.x & 31;
  int nt = blockIdx.x >> 5;
  gemm128_body<float>(Z, wot, bo, out, mt, nt);
}

// ---------------- flash attention ----------------
// grid: 512 blocks = (b,h) x 16 q-tiles (qt fastest). block = 256 thr = 4 waves.
// wave wv owns q rows [qt*128 + wv*32, +32). KV tiles of 64.
__global__ __launch_bounds__(256) void flash_attn(const bf16* __restrict__ Qb,
                                                  const bf16* __restrict__ Kb,
                                                  const bf16* __restrict__ Vb,
                                                  bf16* __restrict__ Zb) {
  __shared__ alignas(16) bf16 Kl[64 * 64];      // [kv][d], slot^=(kv&7)
  __shared__ alignas(16) bf16 Vt[64 * 64];      // [d][kv], slot^=(d&7)
  __shared__ alignas(16) bf16 Pl[4][32 * 64];   // per-wave [q][kv], slot^=(q&7)

  const int lane = threadIdx.x & 63, wv = threadIdx.x >> 6;
  const int qt = blockIdx.x & 15;
  const int bh = blockIdx.x >> 4;
  const int bb = bh >> 4, h = bh & 15;
  const size_t base = ((size_t)bb * SEQ) * DM + h * DHD;
  const int q0 = qt * 128 + wv * 32;

  short8 qf[2][2];
#pragma unroll
  for (int mi = 0; mi < 2; ++mi)
#pragma unroll
    for (int ks = 0; ks < 2; ++ks) {
      int qr = q0 + mi * 16 + (lane & 15);
      int d = ks * 32 + (lane >> 4) * 8;
      qf[mi][ks] = *(const short8*)(Qb + base + (size_t)qr * DM + d);
    }

  f32x4 zacc[2][4];
  float mrow[2][4], lrow[2][4];
#pragma unroll
  for (int mi = 0; mi < 2; ++mi) {
#pragma unroll
    for (int ni = 0; ni < 4; ++ni) zacc[mi][ni] = (f32x4){0.f, 0.f, 0.f, 0.f};
#pragma unroll
    for (int j = 0; j < 4; ++j) { mrow[mi][j] = -1e30f; lrow[mi][j] = 0.f; }
  }

  const int ntiles = 2 * qt + 2;
  for (int t = 0; t < ntiles; ++t) {
    const int kv0 = t * 64;
    // stage K tile (async, swizzled source -> linear LDS)
#pragma unroll
    for (int c = 0; c < 2; ++c) {
      int li0 = wv * 64 + c * 256;
      int li = li0 + lane;
      int row = li >> 3, sl = li & 7;
      int gs = sl ^ (row & 7);
      __builtin_amdgcn_global_load_lds((const AS1 void*)(Kb + base + (size_t)(kv0 + row) * DM + gs * 8),
                                       (AS3 void*)(&Kl[li0 * 8]), 16, 0, 0);
    }
    // stage V transposed (reg transpose, swizzled)
    {
      int kv = threadIdx.x >> 2;
      int d0 = (threadIdx.x & 3) * 16;
      const bf16* src = Vb + base + (size_t)(kv0 + kv) * DM + d0;
      short8 v0 = *(const short8*)(src);
      short8 v1 = *(const short8*)(src + 8);
      short* Vts = (short*)Vt;
#pragma unroll
      for (int j = 0; j < 8; ++j) {
        int d = d0 + j;
        Vts[d * 64 + (((kv >> 3) ^ (d & 7)) << 3) + (kv & 7)] = v0[j];
        int d2 = d0 + 8 + j;
        Vts[d2 * 64 + (((kv >> 3) ^ (d2 & 7)) << 3) + (kv & 7)] = v1[j];
      }
    }
    __syncthreads();

    if (kv0 <= q0 + 31) {  // wave-level causal skip
      short8 kf[4][2];
#pragma unroll
      for (int ni = 0; ni < 4; ++ni)
#pragma unroll
        for (int ks = 0; ks < 2; ++ks) {
          int kr = ni * 16 + (lane & 15);
          int sl = (lane >> 4) + 4 * ks;
          kf[ni][ks] = *(const short8*)(&Kl[kr * 64 + ((sl ^ (kr & 7)) << 3)]);
        }
      f32x4 sacc[2][4];
#pragma unroll
      for (int mi = 0; mi < 2; ++mi)
#pragma unroll
        for (int ni = 0; ni < 4; ++ni) sacc[mi][ni] = (f32x4){0.f, 0.f, 0.f, 0.f};
#pragma unroll
      for (int mi = 0; mi < 2; ++mi)
#pragma unroll
        for (int ni = 0; ni < 4; ++ni)
#pragma unroll
          for (int ks = 0; ks < 2; ++ks)
            sacc[mi][ni] = __builtin_amdgcn_mfma_f32_16x16x32_bf16(qf[mi][ks], kf[ni][ks], sacc[mi][ni], 0, 0, 0);

      // scale + causal mask (in place)
#pragma unroll
      for (int mi = 0; mi < 2; ++mi)
#pragma unroll
        for (int ni = 0; ni < 4; ++ni)
#pragma unroll
          for (int j = 0; j < 4; ++j) {
            int qr = q0 + mi * 16 + (lane >> 4) * 4 + j;
            int kvc = kv0 + ni * 16 + (lane & 15);
            float v = sacc[mi][ni][j] * 0.125f;
            sacc[mi][ni][j] = (kvc > qr) ? -1e30f : v;
          }

      // row max over this tile
      float tm[2][4];
#pragma unroll
      for (int mi = 0; mi < 2; ++mi)
#pragma unroll
        for (int j = 0; j < 4; ++j) {
          float v = sacc[mi][0][j];
#pragma unroll
          for (int ni = 1; ni < 4; ++ni) v = fmaxf(v, sacc[mi][ni][j]);
#pragma unroll
          for (int o = 1; o < 16; o <<= 1) v = fmaxf(v, __shfl_xor(v, o));
          tm[mi][j] = v;
        }

      float al[2][4], ts[2][4];
#pragma unroll
      for (int mi = 0; mi < 2; ++mi)
#pragma unroll
        for (int j = 0; j < 4; ++j) {
          float mn = fmaxf(mrow[mi][j], tm[mi][j]);
          al[mi][j] = __expf(mrow[mi][j] - mn);
          mrow[mi][j] = mn;
          ts[mi][j] = 0.f;
        }
#pragma unroll
      for (int mi = 0; mi < 2; ++mi)
#pragma unroll
        for (int ni = 0; ni < 4; ++ni)
#pragma unroll
          for (int j = 0; j < 4; ++j) {
            float p = __expf(sacc[mi][ni][j] - mrow[mi][j]);
            sacc[mi][ni][j] = p;
            ts[mi][j] += p;
          }
#pragma unroll
      for (int mi = 0; mi < 2; ++mi)
#pragma unroll
        for (int j = 0; j < 4; ++j) {
          float v = ts[mi][j];
#pragma unroll
          for (int o = 1; o < 16; o <<= 1) v += __shfl_xor(v, o);
          lrow[mi][j] = lrow[mi][j] * al[mi][j] + v;
        }
#pragma unroll
      for (int mi = 0; mi < 2; ++mi)
#pragma unroll
        for (int ni = 0; ni < 4; ++ni)
#pragma unroll
          for (int j = 0; j < 4; ++j) zacc[mi][ni][j] *= al[mi][j];

      // write P to per-wave LDS (swizzled)
      short* Ps = (short*)Pl[wv];
#pragma unroll
      for (int mi = 0; mi < 2; ++mi)
#pragma unroll
        for (int ni = 0; ni < 4; ++ni)
#pragma unroll
          for (int j = 0; j < 4; ++j) {
            int r = mi * 16 + (lane >> 4) * 4 + j;
            int cc = ni * 16 + (lane & 15);
            Ps[r * 64 + (((cc >> 3) ^ (r & 7)) << 3) + (cc & 7)] = f2b(sacc[mi][ni][j]);
          }
      asm volatile("s_waitcnt lgkmcnt(0)" ::: "memory");

      // PV
      short8 pf[2][2], vf[4][2];
#pragma unroll
      for (int mi = 0; mi < 2; ++mi)
#pragma unroll
        for (int ks = 0; ks < 2; ++ks) {
          int r = mi * 16 + (lane & 15);
          int sl = (lane >> 4) + 4 * ks;
          pf[mi][ks] = *(const short8*)(&Pl[wv][r * 64 + ((sl ^ (r & 7)) << 3)]);
        }
#pragma unroll
      for (int ni = 0; ni < 4; ++ni)
#pragma unroll
        for (int ks = 0; ks < 2; ++ks) {
          int d = ni * 16 + (lane & 15);
          int sl = (lane >> 4) + 4 * ks;
          vf[ni][ks] = *(const short8*)(&Vt[d * 64 + ((sl ^ (d & 7)) << 3)]);
        }
#pragma unroll
      for (int mi = 0; mi < 2; ++mi)
#pragma unroll
        for (int ni = 0; ni < 4; ++ni)
#pragma unroll
          for (int ks = 0; ks < 2; ++ks)
            zacc[mi][ni] = __builtin_amdgcn_mfma_f32_16x16x32_bf16(pf[mi][ks], vf[ni][ks], zacc[mi][ni], 0, 0, 0);
    }
    __syncthreads();
  }

#pragma unroll
  for (int mi = 0; mi < 2; ++mi)
#pragma unroll
    for (int ni = 0; ni < 4; ++ni)
#pragma unroll
      for (int j = 0; j < 4; ++j) {
        int qr = q0 + mi * 16 + (lane >> 4) * 4 + j;
        int d = ni * 16 + (lane & 15);
        float z = zacc[mi][ni][j] / lrow[mi][j];
        Zb[base + (size_t)qr * DM + d] = __float2bfloat16(z);
      }
}

extern "C" void kernel_launch(void* const* d_in, const int* in_sizes, int n_in,
                              void* d_out, int out_size, void* d_ws, size_t ws_size,
                              hipStream_t stream) {
  (void)in_sizes; (void)n_in; (void)out_size; (void)ws_size;
  const float* x = (const float*)d_in[0];
  const float* pos = (const float*)d_in[1];
  const float* WQ = (const float*)d_in[2];
  const float* bQ = (const float*)d_in[3];
  const float* WK = (const float*)d_in[4];
  const float* bK = (const float*)d_in[5];
  const float* WV = (const float*)d_in[6];
  const float* bV = (const float*)d_in[7];
  const float* WO = (const float*)d_in[8];
  const float* bO = (const float*)d_in[9];
  float* out = (float*)d_out;

  bf16* ws = (bf16*)d_ws;
  size_t off = 0;
  bf16* aib = ws + off; off += (size_t)MROWS * DM;
  bf16* xb  = ws + off; off += (size_t)MROWS * DM;
  bf16* wqt = ws + off; off += (size_t)DM * DM;
  bf16* wkt = ws + off; off += (size_t)DM * DM;
  bf16* wvt = ws + off; off += (size_t)DM * DM;
  bf16* wot = ws + off; off += (size_t)DM * DM;
  bf16* Qb  = ws + off; off += (size_t)MROWS * DM;
  bf16* Kb  = ws + off; off += (size_t)MROWS * DM;
  bf16* Vb  = ws + off; off += (size_t)MROWS * DM;
  bf16* Zb  = ws + off; off += (size_t)MROWS * DM;

  prep_inputs<<<(MROWS * DM / 4 + 255) / 256, 256, 0, stream>>>(x, pos, xb, aib);
  dim3 gq(1, 16, 16);
  transpose_w<<<gq, 256, 0, stream>>>(WQ, wqt, 1024, 64);
  transpose_w<<<gq, 256, 0, stream>>>(WK, wkt, 1024, 64);
  transpose_w<<<gq, 256, 0, stream>>>(WV, wvt, 1024, 64);
  dim3 go(16, 16, 1);
  transpose_w<<<go, 256, 0, stream>>>(WO, wot, 1024, 1024);
  qkv_gemm<<<768, 256, 0, stream>>>(aib, xb, wqt, wkt, wvt, bQ, bK, bV, Qb, Kb, Vb);
  flash_attn<<<512, 256, 0, stream>>>(Qb, Kb, Vb, Zb);
  o_gemm<<<256, 256, 0, stream>>>(Zb, wot, bO, out);
}

// Round 2
// 170.290 us; speedup vs baseline: 1.1642x; 1.1642x over previous
//
#include <hip/hip_runtime.h>
#include <hip/hip_bf16.h>
#include <stdint.h>

typedef __hip_bfloat16 bf16;
typedef __attribute__((ext_vector_type(8))) short short8;
typedef __attribute__((ext_vector_type(4))) short short4v;
typedef __attribute__((ext_vector_type(4))) float f32x4;

#define AS1 __attribute__((address_space(1)))
#define AS3 __attribute__((address_space(3)))

static constexpr int SEQ = 2048, DM = 1024, DHD = 64;
static constexpr int MROWS = 2 * SEQ;  // 4096

__device__ __forceinline__ short f2b(float f) {
  __hip_bfloat16 h = __float2bfloat16(f);
  return *reinterpret_cast<short*>(&h);
}

// ---------------- prep: x -> bf16, x+pos -> bf16 ----------------
__global__ __launch_bounds__(256) void prep_inputs(const float* __restrict__ x,
                                                   const float* __restrict__ pos,
                                                   bf16* __restrict__ xb,
                                                   bf16* __restrict__ aib) {
  int i = blockIdx.x * 256 + threadIdx.x;
  const int n4 = MROWS * DM / 4;
  if (i >= n4) return;
  f32x4 xv = ((const f32x4*)x)[i];
  f32x4 pv = ((const f32x4*)pos)[i];
  short4v xo, ao;
#pragma unroll
  for (int j = 0; j < 4; ++j) {
    xo[j] = f2b(xv[j]);
    ao[j] = f2b(xv[j] + pv[j]);
  }
  ((short4v*)xb)[i] = xo;
  ((short4v*)aib)[i] = ao;
}

// ---------------- weight transpose: [R][C] f32 -> [C][R] bf16 (per z-slice) --
__global__ __launch_bounds__(256) void transpose_w(const float* __restrict__ in,
                                                   bf16* __restrict__ out, int R, int C) {
  __shared__ float t[64][65];
  int ct = blockIdx.x, rt = blockIdx.y, z = blockIdx.z;
  in += (size_t)z * R * C;
  out += (size_t)z * R * C;
  int c = threadIdx.x & 63, g = threadIdx.x >> 6;
#pragma unroll
  for (int j = 0; j < 16; ++j) {
    int r = g * 16 + j;
    t[r][c] = in[(size_t)(rt * 64 + r) * C + (ct * 64 + c)];
  }
  __syncthreads();
#pragma unroll
  for (int j = 0; j < 16; ++j) {
    int rr = g * 16 + j;
    out[(size_t)(ct * 64 + rr) * R + (rt * 64 + c)] = __float2bfloat16(t[c][rr]);
  }
}

// ---------------- 128x128 GEMM body (A[M][1024] bf16, Bt[N][1024] bf16) -----
// MODE 0: bf16 row-major out. MODE 1: f32 row-major out. MODE 2: bf16 out
// transposed per-head into Vt[bh][d][s] (for attention's V operand).
template <int MODE, typename OutT>
__device__ __forceinline__ void gemm128_body(const bf16* __restrict__ A,
                                             const bf16* __restrict__ Bt,
                                             const float* __restrict__ bias,
                                             OutT* __restrict__ C, int mt, int nt,
                                             float scale) {
  __shared__ alignas(16) bf16 Al[128 * 32];
  __shared__ alignas(16) bf16 Bl[128 * 32];
  const int lane = threadIdx.x & 63, wv = threadIdx.x >> 6;
  const int wr = wv >> 1, wc = wv & 1;
  const bf16* Ab = A + (size_t)mt * 128 * DM;
  const bf16* Bb = Bt + (size_t)nt * 128 * DM;

  f32x4 acc[4][4];
#pragma unroll
  for (int i = 0; i < 4; ++i)
#pragma unroll
    for (int j = 0; j < 4; ++j) acc[i][j] = (f32x4){0.f, 0.f, 0.f, 0.f};

  for (int kt = 0; kt < DM / 32; ++kt) {
    int k0 = kt * 32;
#pragma unroll
    for (int c = 0; c < 2; ++c) {
      int li0 = wv * 64 + c * 256;
      int li = li0 + lane;
      int row = li >> 2, sl = li & 3;
      int gs = sl ^ ((row >> 1) & 3);
      __builtin_amdgcn_global_load_lds((const AS1 void*)(Ab + (size_t)row * DM + k0 + gs * 8),
                                       (AS3 void*)(&Al[li0 * 8]), 16, 0, 0);
    }
#pragma unroll
    for (int c = 0; c < 2; ++c) {
      int li0 = wv * 64 + c * 256;
      int li = li0 + lane;
      int row = li >> 2, sl = li & 3;
      int gs = sl ^ ((row >> 1) & 3);
      __builtin_amdgcn_global_load_lds((const AS1 void*)(Bb + (size_t)row * DM + k0 + gs * 8),
                                       (AS3 void*)(&Bl[li0 * 8]), 16, 0, 0);
    }
    __syncthreads();

    short8 af[4], bfr[4];
    const int kb = lane >> 4;
#pragma unroll
    for (int mi = 0; mi < 4; ++mi) {
      int r = wr * 64 + mi * 16 + (lane & 15);
      af[mi] = *(const short8*)(&Al[r * 32 + ((kb ^ ((r >> 1) & 3)) << 3)]);
    }
#pragma unroll
    for (int ni = 0; ni < 4; ++ni) {
      int r = wc * 64 + ni * 16 + (lane & 15);
      bfr[ni] = *(const short8*)(&Bl[r * 32 + ((kb ^ ((r >> 1) & 3)) << 3)]);
    }
#pragma unroll
    for (int mi = 0; mi < 4; ++mi)
#pragma unroll
      for (int ni = 0; ni < 4; ++ni)
        acc[mi][ni] = __builtin_amdgcn_mfma_f32_16x16x32_bf16(af[mi], bfr[ni], acc[mi][ni], 0, 0, 0);
    __syncthreads();
  }

#pragma unroll
  for (int mi = 0; mi < 4; ++mi) {
#pragma unroll
    for (int ni = 0; ni < 4; ++ni) {
      int col = nt * 128 + wc * 64 + ni * 16 + (lane & 15);
      float bv = bias[col];
      if constexpr (MODE == 2) {
        // transposed V write: Vt[bh][d][s], 4 consecutive s per lane -> 8B store
        int row0 = mt * 128 + wr * 64 + mi * 16 + (lane >> 4) * 4;
        int bb = row0 >> 11, s = row0 & 2047;
        int h = col >> 6, d = col & 63;
        short4v o;
#pragma unroll
        for (int j = 0; j < 4; ++j) o[j] = f2b(acc[mi][ni][j] + bv);
        *(short4v*)((bf16*)C + ((size_t)((bb * 16 + h) * 64 + d)) * SEQ + s) = o;
      } else {
#pragma unroll
        for (int j = 0; j < 4; ++j) {
          int row = mt * 128 + wr * 64 + mi * 16 + (lane >> 4) * 4 + j;
          float v = (acc[mi][ni][j] + bv) * scale;
          if constexpr (MODE == 0) {
            C[(size_t)row * DM + col] = __float2bfloat16(v);
          } else {
            C[(size_t)row * DM + col] = v;
          }
        }
      }
    }
  }
}

__global__ __launch_bounds__(256) void qkv_gemm(const bf16* __restrict__ aib,
                                                const bf16* __restrict__ xb,
                                                const bf16* __restrict__ wqt,
                                                const bf16* __restrict__ wkt,
                                                const bf16* __restrict__ wvt,
                                                const float* __restrict__ bq,
                                                const float* __restrict__ bk,
                                                const float* __restrict__ bv,
                                                bf16* __restrict__ Q, bf16* __restrict__ K,
                                                bf16* __restrict__ Vt) {
  int mt = blockIdx.x & 31;
  int nt = (blockIdx.x >> 5) & 7;
  int mat = blockIdx.x >> 8;
  if (mat == 0) {
    gemm128_body<0>(aib, wqt, bq, Q, mt, nt, 0.125f);  // Q prescaled by 1/sqrt(64)
  } else if (mat == 1) {
    gemm128_body<0>(aib, wkt, bk, K, mt, nt, 1.0f);
  } else {
    gemm128_body<2>(xb, wvt, bv, Vt, mt, nt, 1.0f);
  }
}

__global__ __launch_bounds__(256) void o_gemm(const bf16* __restrict__ Z,
                                              const bf16* __restrict__ wot,
                                              const float* __restrict__ bo,
                                              float* __restrict__ out) {
  int mt = blockIdx.x & 31;
  int nt = blockIdx.x >> 5;
  gemm128_body<1>(Z, wot, bo, out, mt, nt, 1.0f);
}

// ---------------- flash attention: 1 wave / 32 q-rows, no barriers ----------
// grid: 2048 blocks x 64 threads. block = (b,h) x wq (wq reversed so long
// blocks dispatch first). K read direct from global (L2-resident), V from
// pre-transposed Vt[bh][d][s]. Only P goes through (per-wave) LDS.
__global__ __launch_bounds__(64) void flash_attn(const bf16* __restrict__ Qb,
                                                 const bf16* __restrict__ Kb,
                                                 const bf16* __restrict__ Vt,
                                                 bf16* __restrict__ Zb) {
  __shared__ alignas(16) bf16 Pl[32 * 64];  // [q][kv], 16B-slot ^= (q&7)

  const int lane = threadIdx.x;
  const int bh = blockIdx.x & 31;
  const int wq = 63 - (blockIdx.x >> 5);
  const int bb = bh >> 4, h = bh & 15;
  const size_t base = ((size_t)bb * SEQ) * DM + h * DHD;
  const size_t vbase = (size_t)bh * DHD * SEQ;
  const int q0 = wq * 32;

  short8 qf[2][2];
#pragma unroll
  for (int mi = 0; mi < 2; ++mi)
#pragma unroll
    for (int ks = 0; ks < 2; ++ks) {
      int qr = q0 + mi * 16 + (lane & 15);
      int d = ks * 32 + (lane >> 4) * 8;
      qf[mi][ks] = *(const short8*)(Qb + base + (size_t)qr * DM + d);
    }

  f32x4 zacc[2][4];
  float mrow[2][4], lrow[2][4];
#pragma unroll
  for (int mi = 0; mi < 2; ++mi) {
#pragma unroll
    for (int ni = 0; ni < 4; ++ni) zacc[mi][ni] = (f32x4){0.f, 0.f, 0.f, 0.f};
#pragma unroll
    for (int j = 0; j < 4; ++j) { mrow[mi][j] = -1e30f; lrow[mi][j] = 0.f; }
  }

  const int ntiles = wq / 2 + 1;
  for (int t = 0; t < ntiles; ++t) {
    const int kv0 = t * 64;

    // QK^T: K fragments straight from global (Q was prescaled by 0.125)
    short8 kf[4][2];
#pragma unroll
    for (int ni = 0; ni < 4; ++ni)
#pragma unroll
      for (int ks = 0; ks < 2; ++ks) {
        int kr = kv0 + ni * 16 + (lane & 15);
        int d = ks * 32 + (lane >> 4) * 8;
        kf[ni][ks] = *(const short8*)(Kb + base + (size_t)kr * DM + d);
      }
    f32x4 sacc[2][4];
#pragma unroll
    for (int mi = 0; mi < 2; ++mi)
#pragma unroll
      for (int ni = 0; ni < 4; ++ni) sacc[mi][ni] = (f32x4){0.f, 0.f, 0.f, 0.f};
#pragma unroll
    for (int mi = 0; mi < 2; ++mi)
#pragma unroll
      for (int ni = 0; ni < 4; ++ni)
#pragma unroll
        for (int ks = 0; ks < 2; ++ks)
          sacc[mi][ni] = __builtin_amdgcn_mfma_f32_16x16x32_bf16(qf[mi][ks], kf[ni][ks], sacc[mi][ni], 0, 0, 0);

    if (t == ntiles - 1) {  // causal mask: only the diagonal tile needs it
#pragma unroll
      for (int mi = 0; mi < 2; ++mi)
#pragma unroll
        for (int ni = 0; ni < 4; ++ni)
#pragma unroll
          for (int j = 0; j < 4; ++j) {
            int qr = q0 + mi * 16 + (lane >> 4) * 4 + j;
            int kvc = kv0 + ni * 16 + (lane & 15);
            if (kvc > qr) sacc[mi][ni][j] = -1e30f;
          }
    }

    // online softmax (rows live across 16-lane groups)
    float tm[2][4];
#pragma unroll
    for (int mi = 0; mi < 2; ++mi)
#pragma unroll
      for (int j = 0; j < 4; ++j) {
        float v = sacc[mi][0][j];
#pragma unroll
        for (int ni = 1; ni < 4; ++ni) v = fmaxf(v, sacc[mi][ni][j]);
#pragma unroll
        for (int o = 1; o < 16; o <<= 1) v = fmaxf(v, __shfl_xor(v, o));
        tm[mi][j] = v;
      }
    float al[2][4], ts[2][4];
#pragma unroll
    for (int mi = 0; mi < 2; ++mi)
#pragma unroll
      for (int j = 0; j < 4; ++j) {
        float mn = fmaxf(mrow[mi][j], tm[mi][j]);
        al[mi][j] = __expf(mrow[mi][j] - mn);
        mrow[mi][j] = mn;
        ts[mi][j] = 0.f;
      }
#pragma unroll
    for (int mi = 0; mi < 2; ++mi)
#pragma unroll
      for (int ni = 0; ni < 4; ++ni)
#pragma unroll
        for (int j = 0; j < 4; ++j) {
          float p = __expf(sacc[mi][ni][j] - mrow[mi][j]);
          sacc[mi][ni][j] = p;
          ts[mi][j] += p;
        }
#pragma unroll
    for (int mi = 0; mi < 2; ++mi)
#pragma unroll
      for (int j = 0; j < 4; ++j) {
        float v = ts[mi][j];
#pragma unroll
        for (int o = 1; o < 16; o <<= 1) v += __shfl_xor(v, o);
        lrow[mi][j] = lrow[mi][j] * al[mi][j] + v;
      }
#pragma unroll
    for (int mi = 0; mi < 2; ++mi)
#pragma unroll
      for (int ni = 0; ni < 4; ++ni)
#pragma unroll
        for (int j = 0; j < 4; ++j) zacc[mi][ni][j] *= al[mi][j];

    // P -> per-wave LDS (swizzled), then read back as A-fragments
    short* Ps = (short*)Pl;
#pragma unroll
    for (int mi = 0; mi < 2; ++mi)
#pragma unroll
      for (int ni = 0; ni < 4; ++ni)
#pragma unroll
        for (int j = 0; j < 4; ++j) {
          int r = mi * 16 + (lane >> 4) * 4 + j;
          int cc = ni * 16 + (lane & 15);
          Ps[r * 64 + (((cc >> 3) ^ (r & 7)) << 3) + (cc & 7)] = f2b(sacc[mi][ni][j]);
        }

    short8 pf[2][2], vf[4][2];
#pragma unroll
    for (int mi = 0; mi < 2; ++mi)
#pragma unroll
      for (int ks = 0; ks < 2; ++ks) {
        int r = mi * 16 + (lane & 15);
        int sl = (lane >> 4) + 4 * ks;
        pf[mi][ks] = *(const short8*)(&Pl[r * 64 + ((sl ^ (r & 7)) << 3)]);
      }
#pragma unroll
    for (int ni = 0; ni < 4; ++ni)
#pragma unroll
      for (int ks = 0; ks < 2; ++ks) {
        int d = ni * 16 + (lane & 15);
        int kv = kv0 + ((lane >> 4) + 4 * ks) * 8;
        vf[ni][ks] = *(const short8*)(Vt + vbase + (size_t)d * SEQ + kv);
      }
#pragma unroll
    for (int mi = 0; mi < 2; ++mi)
#pragma unroll
      for (int ni = 0; ni < 4; ++ni)
#pragma unroll
        for (int ks = 0; ks < 2; ++ks)
          zacc[mi][ni] = __builtin_amdgcn_mfma_f32_16x16x32_bf16(pf[mi][ks], vf[ni][ks], zacc[mi][ni], 0, 0, 0);
  }

#pragma unroll
  for (int mi = 0; mi < 2; ++mi)
#pragma unroll
    for (int ni = 0; ni < 4; ++ni)
#pragma unroll
      for (int j = 0; j < 4; ++j) {
        int qr = q0 + mi * 16 + (lane >> 4) * 4 + j;
        int d = ni * 16 + (lane & 15);
        float z = zacc[mi][ni][j] / lrow[mi][j];
        Zb[base + (size_t)qr * DM + d] = __float2bfloat16(z);
      }
}

extern "C" void kernel_launch(void* const* d_in, const int* in_sizes, int n_in,
                              void* d_out, int out_size, void* d_ws, size_t ws_size,
                              hipStream_t stream) {
  (void)in_sizes; (void)n_in; (void)out_size; (void)ws_size;
  const float* x = (const float*)d_in[0];
  const float* pos = (const float*)d_in[1];
  const float* WQ = (const float*)d_in[2];
  const float* bQ = (const float*)d_in[3];
  const float* WK = (const float*)d_in[4];
  const float* bK = (const float*)d_in[5];
  const float* WV = (const float*)d_in[6];
  const float* bV = (const float*)d_in[7];
  const float* WO = (const float*)d_in[8];
  const float* bO = (const float*)d_in[9];
  float* out = (float*)d_out;

  bf16* ws = (bf16*)d_ws;
  size_t off = 0;
  bf16* aib = ws + off; off += (size_t)MROWS * DM;
  bf16* xb  = ws + off; off += (size_t)MROWS * DM;
  bf16* wqt = ws + off; off += (size_t)DM * DM;
  bf16* wkt = ws + off; off += (size_t)DM * DM;
  bf16* wvt = ws + off; off += (size_t)DM * DM;
  bf16* wot = ws + off; off += (size_t)DM * DM;
  bf16* Qb  = ws + off; off += (size_t)MROWS * DM;
  bf16* Kb  = ws + off; off += (size_t)MROWS * DM;
  bf16* Vtb = ws + off; off += (size_t)MROWS * DM;  // [bh][d][s]
  bf16* Zb  = ws + off; off += (size_t)MROWS * DM;

  prep_inputs<<<(MROWS * DM / 4 + 255) / 256, 256, 0, stream>>>(x, pos, xb, aib);
  dim3 gq(1, 16, 16);
  transpose_w<<<gq, 256, 0, stream>>>(WQ, wqt, 1024, 64);
  transpose_w<<<gq, 256, 0, stream>>>(WK, wkt, 1024, 64);
  transpose_w<<<gq, 256, 0, stream>>>(WV, wvt, 1024, 64);
  dim3 go(16, 16, 1);
  transpose_w<<<go, 256, 0, stream>>>(WO, wot, 1024, 1024);
  qkv_gemm<<<768, 256, 0, stream>>>(aib, xb, wqt, wkt, wvt, bQ, bK, bV, Qb, Kb, Vtb);
  flash_attn<<<2048, 64, 0, stream>>>(Qb, Kb, Vtb, Zb);
  o_gemm<<<256, 256, 0, stream>>>(Zb, wot, bO, out);
}

// Round 3
// 156.662 us; speedup vs baseline: 1.2654x; 1.0870x over previous
//
#include <hip/hip_runtime.h>
#include <hip/hip_bf16.h>
#include <stdint.h>

typedef __hip_bfloat16 bf16;
typedef __attribute__((ext_vector_type(8))) short short8;
typedef __attribute__((ext_vector_type(4))) short short4v;
typedef __attribute__((ext_vector_type(4))) float f32x4;
typedef __attribute__((ext_vector_type(16))) float f32x16;
typedef __attribute__((ext_vector_type(4))) unsigned uint4v;

#define AS1 __attribute__((address_space(1)))
#define AS3 __attribute__((address_space(3)))

static constexpr int SEQ = 2048, DM = 1024, DHD = 64;
static constexpr int MROWS = 2 * SEQ;  // 4096

__device__ __forceinline__ short f2b(float f) {
  __hip_bfloat16 h = __float2bfloat16(f);
  return *reinterpret_cast<short*>(&h);
}

union U8 { uint4v u; short8 s; };

// ---------------- prep: x -> bf16, x+pos -> bf16 ----------------
__global__ __launch_bounds__(256) void prep_inputs(const float* __restrict__ x,
                                                   const float* __restrict__ pos,
                                                   bf16* __restrict__ xb,
                                                   bf16* __restrict__ aib) {
  int i = blockIdx.x * 256 + threadIdx.x;
  const int n4 = MROWS * DM / 4;
  if (i >= n4) return;
  f32x4 xv = ((const f32x4*)x)[i];
  f32x4 pv = ((const f32x4*)pos)[i];
  short4v xo, ao;
#pragma unroll
  for (int j = 0; j < 4; ++j) {
    xo[j] = f2b(xv[j]);
    ao[j] = f2b(xv[j] + pv[j]);
  }
  ((short4v*)xb)[i] = xo;
  ((short4v*)aib)[i] = ao;
}

// ---------------- weight transpose: [R][C] f32 -> [C][R] bf16 (per z-slice) --
__global__ __launch_bounds__(256) void transpose_w(const float* __restrict__ in,
                                                   bf16* __restrict__ out, int R, int C) {
  __shared__ float t[64][65];
  int ct = blockIdx.x, rt = blockIdx.y, z = blockIdx.z;
  in += (size_t)z * R * C;
  out += (size_t)z * R * C;
  int c = threadIdx.x & 63, g = threadIdx.x >> 6;
#pragma unroll
  for (int j = 0; j < 16; ++j) {
    int r = g * 16 + j;
    t[r][c] = in[(size_t)(rt * 64 + r) * C + (ct * 64 + c)];
  }
  __syncthreads();
#pragma unroll
  for (int j = 0; j < 16; ++j) {
    int rr = g * 16 + j;
    out[(size_t)(ct * 64 + rr) * R + (rt * 64 + c)] = __float2bfloat16(t[c][rr]);
  }
}

// ---------------- 128x128 GEMM body (A[M][1024] bf16, Bt[N][1024] bf16) -----
// MODE 0: bf16 row-major out (scaled). MODE 1: f32 row-major out. MODE 2: bf16
// out transposed per-head into Vt[bh][d][s].
template <int MODE, typename OutT>
__device__ __forceinline__ void gemm128_body(const bf16* __restrict__ A,
                                             const bf16* __restrict__ Bt,
                                             const float* __restrict__ bias,
                                             OutT* __restrict__ C, int mt, int nt,
                                             float scale) {
  __shared__ alignas(16) bf16 Al[128 * 32];
  __shared__ alignas(16) bf16 Bl[128 * 32];
  const int lane = threadIdx.x & 63, wv = threadIdx.x >> 6;
  const int wr = wv >> 1, wc = wv & 1;
  const bf16* Ab = A + (size_t)mt * 128 * DM;
  const bf16* Bb = Bt + (size_t)nt * 128 * DM;

  f32x4 acc[4][4];
#pragma unroll
  for (int i = 0; i < 4; ++i)
#pragma unroll
    for (int j = 0; j < 4; ++j) acc[i][j] = (f32x4){0.f, 0.f, 0.f, 0.f};

  for (int kt = 0; kt < DM / 32; ++kt) {
    int k0 = kt * 32;
#pragma unroll
    for (int c = 0; c < 2; ++c) {
      int li0 = wv * 64 + c * 256;
      int li = li0 + lane;
      int row = li >> 2, sl = li & 3;
      int gs = sl ^ ((row >> 1) & 3);
      __builtin_amdgcn_global_load_lds((const AS1 void*)(Ab + (size_t)row * DM + k0 + gs * 8),
                                       (AS3 void*)(&Al[li0 * 8]), 16, 0, 0);
    }
#pragma unroll
    for (int c = 0; c < 2; ++c) {
      int li0 = wv * 64 + c * 256;
      int li = li0 + lane;
      int row = li >> 2, sl = li & 3;
      int gs = sl ^ ((row >> 1) & 3);
      __builtin_amdgcn_global_load_lds((const AS1 void*)(Bb + (size_t)row * DM + k0 + gs * 8),
                                       (AS3 void*)(&Bl[li0 * 8]), 16, 0, 0);
    }
    __syncthreads();

    short8 af[4], bfr[4];
    const int kb = lane >> 4;
#pragma unroll
    for (int mi = 0; mi < 4; ++mi) {
      int r = wr * 64 + mi * 16 + (lane & 15);
      af[mi] = *(const short8*)(&Al[r * 32 + ((kb ^ ((r >> 1) & 3)) << 3)]);
    }
#pragma unroll
    for (int ni = 0; ni < 4; ++ni) {
      int r = wc * 64 + ni * 16 + (lane & 15);
      bfr[ni] = *(const short8*)(&Bl[r * 32 + ((kb ^ ((r >> 1) & 3)) << 3)]);
    }
#pragma unroll
    for (int mi = 0; mi < 4; ++mi)
#pragma unroll
      for (int ni = 0; ni < 4; ++ni)
        acc[mi][ni] = __builtin_amdgcn_mfma_f32_16x16x32_bf16(af[mi], bfr[ni], acc[mi][ni], 0, 0, 0);
    __syncthreads();
  }

#pragma unroll
  for (int mi = 0; mi < 4; ++mi) {
#pragma unroll
    for (int ni = 0; ni < 4; ++ni) {
      int col = nt * 128 + wc * 64 + ni * 16 + (lane & 15);
      float bv = bias[col];
      if constexpr (MODE == 2) {
        int row0 = mt * 128 + wr * 64 + mi * 16 + (lane >> 4) * 4;
        int bb = row0 >> 11, s = row0 & 2047;
        int h = col >> 6, d = col & 63;
        short4v o;
#pragma unroll
        for (int j = 0; j < 4; ++j) o[j] = f2b(acc[mi][ni][j] + bv);
        *(short4v*)((bf16*)C + ((size_t)((bb * 16 + h) * 64 + d)) * SEQ + s) = o;
      } else {
#pragma unroll
        for (int j = 0; j < 4; ++j) {
          int row = mt * 128 + wr * 64 + mi * 16 + (lane >> 4) * 4 + j;
          float v = (acc[mi][ni][j] + bv) * scale;
          if constexpr (MODE == 0) {
            C[(size_t)row * DM + col] = __float2bfloat16(v);
          } else {
            C[(size_t)row * DM + col] = v;
          }
        }
      }
    }
  }
}

// Q prescale: (1/sqrt(64)) * log2(e) so attention uses exp2
static constexpr float QSCALE = 0.125f * 1.4426950408889634f;

__global__ __launch_bounds__(256) void qkv_gemm(const bf16* __restrict__ aib,
                                                const bf16* __restrict__ xb,
                                                const bf16* __restrict__ wqt,
                                                const bf16* __restrict__ wkt,
                                                const bf16* __restrict__ wvt,
                                                const float* __restrict__ bq,
                                                const float* __restrict__ bk,
                                                const float* __restrict__ bv,
                                                bf16* __restrict__ Q, bf16* __restrict__ K,
                                                bf16* __restrict__ Vt) {
  int mt = blockIdx.x & 31;
  int nt = (blockIdx.x >> 5) & 7;
  int mat = blockIdx.x >> 8;
  if (mat == 0) {
    gemm128_body<0>(aib, wqt, bq, Q, mt, nt, QSCALE);
  } else if (mat == 1) {
    gemm128_body<0>(aib, wkt, bk, K, mt, nt, 1.0f);
  } else {
    gemm128_body<2>(xb, wvt, bv, Vt, mt, nt, 1.0f);
  }
}

__global__ __launch_bounds__(256) void o_gemm(const bf16* __restrict__ Z,
                                              const bf16* __restrict__ wot,
                                              const float* __restrict__ bo,
                                              float* __restrict__ out) {
  int mt = blockIdx.x & 31;
  int nt = blockIdx.x >> 5;
  gemm128_body<1>(Z, wot, bo, out, mt, nt, 1.0f);
}

// ---------------- flash attention: swapped-QK^T, 1 wave / 32 q-rows ----------
// S^T = mfma32x32x16(K,Q): lane owns full q-row (q=lane&31) -> scalar m/l,
// in-register softmax. PV computes Z^T = mfma(V^T, P) so rescale is scalar.
// K double-buffered in regs (prefetch); V loads issued at tile top.
__global__ __launch_bounds__(64) void flash_attn(const bf16* __restrict__ Qb,
                                                 const bf16* __restrict__ Kb,
                                                 const bf16* __restrict__ Vt,
                                                 bf16* __restrict__ Zb) {
  __shared__ unsigned Zl[32 * 32];  // 4KB, final ZT->Z transpose

  const int lane = threadIdx.x;
  const int qln = lane & 31;
  const int hi8 = (lane >> 5) * 8;
  const bool hib = lane >= 32;
  const int bh = blockIdx.x & 31;
  const int r = blockIdx.x >> 5;
  const int r0 = r & 7, kk = r >> 3;
  // balanced pairing: per-CU wave pairs (w, 63-w)
  const int wq = (kk < 4) ? (4 * r0 + kk) : (63 - (4 * r0 + (kk - 4)));
  const int bb = bh >> 4, h = bh & 15;
  const size_t base = ((size_t)bb * SEQ) * DM + h * DHD;
  const size_t vbase = (size_t)bh * DHD * SEQ;
  const int q0 = wq * 32;
  const int ntiles = wq / 2 + 1;

  // Q fragments (B operand): row q = q0+qln, k = kc*16 + hi8 + e
  short8 qf[4];
#pragma unroll
  for (int kc = 0; kc < 4; ++kc)
    qf[kc] = *(const short8*)(Qb + base + (size_t)(q0 + qln) * DM + kc * 16 + hi8);

  f32x16 zacc[2];
#pragma unroll
  for (int i = 0; i < 16; ++i) { zacc[0][i] = 0.f; zacc[1][i] = 0.f; }
  float mrun = -1e30f, lrun = 0.f;

  auto loadK = [&](short8(&kf)[2][4], int tt) {
#pragma unroll
    for (int ni = 0; ni < 2; ++ni)
#pragma unroll
      for (int kc = 0; kc < 4; ++kc)
        kf[ni][kc] = *(const short8*)(Kb + base + (size_t)(tt * 64 + 32 * ni + qln) * DM + kc * 16 + hi8);
  };

  auto computeT = [&](short8(&kf)[2][4], short8(&kfn)[2][4], int t, bool pref) {
    const int kv0 = t * 64;
    // V fragments for this tile (A operand of PV): row d = 32*dj+qln, k = kv
    short8 vf[2][4];
#pragma unroll
    for (int dj = 0; dj < 2; ++dj)
#pragma unroll
      for (int c = 0; c < 4; ++c)
        vf[dj][c] = *(const short8*)(Vt + vbase + (size_t)(32 * dj + qln) * SEQ + kv0 + c * 16 + hi8);

    // S^T[kv][q]
    f32x16 s[2];
#pragma unroll
    for (int i = 0; i < 16; ++i) { s[0][i] = 0.f; s[1][i] = 0.f; }
#pragma unroll
    for (int kc = 0; kc < 4; ++kc) {
      s[0] = __builtin_amdgcn_mfma_f32_32x32x16_bf16(kf[0][kc], qf[kc], s[0], 0, 0, 0);
      s[1] = __builtin_amdgcn_mfma_f32_32x32x16_bf16(kf[1][kc], qf[kc], s[1], 0, 0, 0);
    }

    if (pref) loadK(kfn, t + 1);  // prefetch next K under softmax

    if (t == ntiles - 1) {  // causal mask, only diagonal tile
      const int qg = q0 + qln;
#pragma unroll
      for (int ni = 0; ni < 2; ++ni)
#pragma unroll
        for (int rr = 0; rr < 16; ++rr) {
          int kv = kv0 + 32 * ni + (rr & 3) + 8 * (rr >> 2) + (hib ? 4 : 0);
          if (kv > qg) s[ni][rr] = -1e30f;
        }
    }

    // row max: in-register tree + 1 cross-half shuffle
    float t8[8];
#pragma unroll
    for (int i = 0; i < 8; ++i)
      t8[i] = fmaxf(fmaxf(s[0][i], s[0][i + 8]), fmaxf(s[1][i], s[1][i + 8]));
    float tm = fmaxf(fmaxf(fmaxf(t8[0], t8[1]), fmaxf(t8[2], t8[3])),
                     fmaxf(fmaxf(t8[4], t8[5]), fmaxf(t8[6], t8[7])));
    tm = fmaxf(tm, __shfl_xor(tm, 32));
    float mn = fmaxf(mrun, tm);
    float al = exp2f(mrun - mn);
    mrun = mn;

    float pacc[4] = {0.f, 0.f, 0.f, 0.f};
#pragma unroll
    for (int ni = 0; ni < 2; ++ni)
#pragma unroll
      for (int rr = 0; rr < 16; ++rr) {
        float p = exp2f(s[ni][rr] - mn);
        s[ni][rr] = p;
        pacc[rr & 3] += p;
      }
    float sum = (pacc[0] + pacc[1]) + (pacc[2] + pacc[3]);
    sum += __shfl_xor(sum, 32);
    lrun = lrun * al + sum;
#pragma unroll
    for (int i = 0; i < 16; ++i) { zacc[0][i] *= al; zacc[1][i] *= al; }

    // P -> bf16 A-fragments: pack pairs, swap halves, select
    unsigned su32[2][8], X[2][8];
#pragma unroll
    for (int ni = 0; ni < 2; ++ni)
#pragma unroll
      for (int tt = 0; tt < 8; ++tt) {
        unsigned lo = (unsigned short)f2b(s[ni][2 * tt]);
        unsigned hh = (unsigned short)f2b(s[ni][2 * tt + 1]);
        su32[ni][tt] = lo | (hh << 16);
      }
#pragma unroll
    for (int ni = 0; ni < 2; ++ni)
#pragma unroll
      for (int tt = 0; tt < 8; ++tt)
        X[ni][tt] = (unsigned)__shfl_xor((int)su32[ni][tt], 32);

    short8 pa[4];
#pragma unroll
    for (int c = 0; c < 4; ++c) {
      int ni = c >> 1, b4 = 4 * (c & 1);
      U8 w;
      w.u[0] = hib ? X[ni][b4 + 2] : su32[ni][b4 + 0];
      w.u[1] = hib ? X[ni][b4 + 3] : su32[ni][b4 + 1];
      w.u[2] = hib ? su32[ni][b4 + 2] : X[ni][b4 + 0];
      w.u[3] = hib ? su32[ni][b4 + 3] : X[ni][b4 + 1];
      pa[c] = w.s;
    }

    // Z^T += V^T * P
#pragma unroll
    for (int c = 0; c < 4; ++c) {
      zacc[0] = __builtin_amdgcn_mfma_f32_32x32x16_bf16(vf[0][c], pa[c], zacc[0], 0, 0, 0);
      zacc[1] = __builtin_amdgcn_mfma_f32_32x32x16_bf16(vf[1][c], pa[c], zacc[1], 0, 0, 0);
    }
  };

  short8 kfA[2][4], kfB[2][4];
  loadK(kfA, 0);
  int t = 0;
  while (true) {
    computeT(kfA, kfB, t, t + 1 < ntiles);
    if (++t >= ntiles) break;
    computeT(kfB, kfA, t, t + 1 < ntiles);
    if (++t >= ntiles) break;
  }

  // normalize + transpose Z^T -> Z via swizzled LDS, coalesced store
  const float rl = 1.0f / lrun;
  const int W8[8] = {0, 1, 4, 5, 8, 9, 12, 13};
#pragma unroll
  for (int dj = 0; dj < 2; ++dj)
#pragma unroll
    for (int tt = 0; tt < 8; ++tt) {
      unsigned lo = (unsigned short)f2b(zacc[dj][2 * tt] * rl);
      unsigned hh = (unsigned short)f2b(zacc[dj][2 * tt + 1] * rl);
      unsigned v = lo | (hh << 16);
      int x = 16 * dj + (hib ? 2 : 0) + W8[tt];
      Zl[qln * 32 + (((x >> 2) ^ (qln & 7)) << 2) + (x & 3)] = v;
    }
  asm volatile("s_waitcnt lgkmcnt(0)" ::: "memory");
  int q2 = lane >> 1, hf = lane & 1;
#pragma unroll
  for (int u = 0; u < 4; ++u) {
    int sl = (hf * 4 + u) ^ (q2 & 7);
    U8 w;
    w.u = *(const uint4v*)&Zl[q2 * 32 + sl * 4];
    *(short8*)(Zb + base + (size_t)(q0 + q2) * DM + hf * 32 + u * 8) = w.s;
  }
}

extern "C" void kernel_launch(void* const* d_in, const int* in_sizes, int n_in,
                              void* d_out, int out_size, void* d_ws, size_t ws_size,
                              hipStream_t stream) {
  (void)in_sizes; (void)n_in; (void)out_size; (void)ws_size;
  const float* x = (const float*)d_in[0];
  const float* pos = (const float*)d_in[1];
  const float* WQ = (const float*)d_in[2];
  const float* bQ = (const float*)d_in[3];
  const float* WK = (const float*)d_in[4];
  const float* bK = (const float*)d_in[5];
  const float* WV = (const float*)d_in[6];
  const float* bV = (const float*)d_in[7];
  const float* WO = (const float*)d_in[8];
  const float* bO = (const float*)d_in[9];
  float* out = (float*)d_out;

  bf16* ws = (bf16*)d_ws;
  size_t off = 0;
  bf16* aib = ws + off; off += (size_t)MROWS * DM;
  bf16* xb  = ws + off; off += (size_t)MROWS * DM;
  bf16* wqt = ws + off; off += (size_t)DM * DM;
  bf16* wkt = ws + off; off += (size_t)DM * DM;
  bf16* wvt = ws + off; off += (size_t)DM * DM;
  bf16* wot = ws + off; off += (size_t)DM * DM;
  bf16* Qb  = ws + off; off += (size_t)MROWS * DM;
  bf16* Kb  = ws + off; off += (size_t)MROWS * DM;
  bf16* Vtb = ws + off; off += (size_t)MROWS * DM;  // [bh][d][s]
  bf16* Zb  = ws + off; off += (size_t)MROWS * DM;

  prep_inputs<<<(MROWS * DM / 4 + 255) / 256, 256, 0, stream>>>(x, pos, xb, aib);
  dim3 gq(1, 16, 16);
  transpose_w<<<gq, 256, 0, stream>>>(WQ, wqt, 1024, 64);
  transpose_w<<<gq, 256, 0, stream>>>(WK, wkt, 1024, 64);
  transpose_w<<<gq, 256, 0, stream>>>(WV, wvt, 1024, 64);
  dim3 go(16, 16, 1);
  transpose_w<<<go, 256, 0, stream>>>(WO, wot, 1024, 1024);
  qkv_gemm<<<768, 256, 0, stream>>>(aib, xb, wqt, wkt, wvt, bQ, bK, bV, Qb, Kb, Vtb);
  flash_attn<<<2048, 64, 0, stream>>>(Qb, Kb, Vtb, Zb);
  o_gemm<<<256, 256, 0, stream>>>(Zb, wot, bO, out);
}

// Round 4
// 151.656 us; speedup vs baseline: 1.3072x; 1.0330x over previous
//
#include <hip/hip_runtime.h>
#include <hip/hip_bf16.h>
#include <stdint.h>

typedef __hip_bfloat16 bf16;
typedef __attribute__((ext_vector_type(8))) short short8;
typedef __attribute__((ext_vector_type(4))) short short4v;
typedef __attribute__((ext_vector_type(4))) float f32x4;
typedef __attribute__((ext_vector_type(16))) float f32x16;
typedef __attribute__((ext_vector_type(4))) unsigned uint4v;

#define AS1 __attribute__((address_space(1)))
#define AS3 __attribute__((address_space(3)))

static constexpr int SEQ = 2048, DM = 1024, DHD = 64;
static constexpr int MROWS = 2 * SEQ;  // 4096

__device__ __forceinline__ short f2b(float f) {
  __hip_bfloat16 h = __float2bfloat16(f);
  return *reinterpret_cast<short*>(&h);
}

__device__ __forceinline__ unsigned pack2(float lo, float hi) {
  float2 fv; fv.x = lo; fv.y = hi;
  union { __hip_bfloat162 h; unsigned u; } cv;
  cv.h = __float22bfloat162_rn(fv);
  return cv.u;
}

union U8 { uint4v u; short8 s; };

// ---------------- prep: x -> bf16, x+pos -> bf16 ----------------
__global__ __launch_bounds__(256) void prep_inputs(const float* __restrict__ x,
                                                   const float* __restrict__ pos,
                                                   bf16* __restrict__ xb,
                                                   bf16* __restrict__ aib) {
  int i = blockIdx.x * 256 + threadIdx.x;
  const int n4 = MROWS * DM / 4;
  if (i >= n4) return;
  f32x4 xv = ((const f32x4*)x)[i];
  f32x4 pv = ((const f32x4*)pos)[i];
  short4v xo, ao;
#pragma unroll
  for (int j = 0; j < 4; ++j) {
    xo[j] = f2b(xv[j]);
    ao[j] = f2b(xv[j] + pv[j]);
  }
  ((short4v*)xb)[i] = xo;
  ((short4v*)aib)[i] = ao;
}

// ---------------- weight transpose: [R][C] f32 -> [C][R] bf16 (per z-slice) --
__global__ __launch_bounds__(256) void transpose_w(const float* __restrict__ in,
                                                   bf16* __restrict__ out, int R, int C) {
  __shared__ float t[64][65];
  int ct = blockIdx.x, rt = blockIdx.y, z = blockIdx.z;
  in += (size_t)z * R * C;
  out += (size_t)z * R * C;
  int c = threadIdx.x & 63, g = threadIdx.x >> 6;
#pragma unroll
  for (int j = 0; j < 16; ++j) {
    int r = g * 16 + j;
    t[r][c] = in[(size_t)(rt * 64 + r) * C + (ct * 64 + c)];
  }
  __syncthreads();
#pragma unroll
  for (int j = 0; j < 16; ++j) {
    int rr = g * 16 + j;
    out[(size_t)(ct * 64 + rr) * R + (rt * 64 + c)] = __float2bfloat16(t[c][rr]);
  }
}

// ---------------- 128x128 GEMM body (A[M][1024] bf16, Bt[N][1024] bf16) -----
// MODE 0: bf16 row-major out (scaled). MODE 1: f32 row-major out. MODE 2: bf16
// out transposed per-head into Vt[bh][d][s].
template <int MODE, typename OutT>
__device__ __forceinline__ void gemm128_body(const bf16* __restrict__ A,
                                             const bf16* __restrict__ Bt,
                                             const float* __restrict__ bias,
                                             OutT* __restrict__ C, int mt, int nt,
                                             float scale) {
  __shared__ alignas(16) bf16 Al[128 * 32];
  __shared__ alignas(16) bf16 Bl[128 * 32];
  const int lane = threadIdx.x & 63, wv = threadIdx.x >> 6;
  const int wr = wv >> 1, wc = wv & 1;
  const bf16* Ab = A + (size_t)mt * 128 * DM;
  const bf16* Bb = Bt + (size_t)nt * 128 * DM;

  f32x4 acc[4][4];
#pragma unroll
  for (int i = 0; i < 4; ++i)
#pragma unroll
    for (int j = 0; j < 4; ++j) acc[i][j] = (f32x4){0.f, 0.f, 0.f, 0.f};

  for (int kt = 0; kt < DM / 32; ++kt) {
    int k0 = kt * 32;
#pragma unroll
    for (int c = 0; c < 2; ++c) {
      int li0 = wv * 64 + c * 256;
      int li = li0 + lane;
      int row = li >> 2, sl = li & 3;
      int gs = sl ^ ((row >> 1) & 3);
      __builtin_amdgcn_global_load_lds((const AS1 void*)(Ab + (size_t)row * DM + k0 + gs * 8),
                                       (AS3 void*)(&Al[li0 * 8]), 16, 0, 0);
    }
#pragma unroll
    for (int c = 0; c < 2; ++c) {
      int li0 = wv * 64 + c * 256;
      int li = li0 + lane;
      int row = li >> 2, sl = li & 3;
      int gs = sl ^ ((row >> 1) & 3);
      __builtin_amdgcn_global_load_lds((const AS1 void*)(Bb + (size_t)row * DM + k0 + gs * 8),
                                       (AS3 void*)(&Bl[li0 * 8]), 16, 0, 0);
    }
    __syncthreads();

    short8 af[4], bfr[4];
    const int kb = lane >> 4;
#pragma unroll
    for (int mi = 0; mi < 4; ++mi) {
      int r = wr * 64 + mi * 16 + (lane & 15);
      af[mi] = *(const short8*)(&Al[r * 32 + ((kb ^ ((r >> 1) & 3)) << 3)]);
    }
#pragma unroll
    for (int ni = 0; ni < 4; ++ni) {
      int r = wc * 64 + ni * 16 + (lane & 15);
      bfr[ni] = *(const short8*)(&Bl[r * 32 + ((kb ^ ((r >> 1) & 3)) << 3)]);
    }
#pragma unroll
    for (int mi = 0; mi < 4; ++mi)
#pragma unroll
      for (int ni = 0; ni < 4; ++ni)
        acc[mi][ni] = __builtin_amdgcn_mfma_f32_16x16x32_bf16(af[mi], bfr[ni], acc[mi][ni], 0, 0, 0);
    __syncthreads();
  }

#pragma unroll
  for (int mi = 0; mi < 4; ++mi) {
#pragma unroll
    for (int ni = 0; ni < 4; ++ni) {
      int col = nt * 128 + wc * 64 + ni * 16 + (lane & 15);
      float bv = bias[col];
      if constexpr (MODE == 2) {
        int row0 = mt * 128 + wr * 64 + mi * 16 + (lane >> 4) * 4;
        int bb = row0 >> 11, s = row0 & 2047;
        int h = col >> 6, d = col & 63;
        short4v o;
#pragma unroll
        for (int j = 0; j < 4; ++j) o[j] = f2b(acc[mi][ni][j] + bv);
        *(short4v*)((bf16*)C + ((size_t)((bb * 16 + h) * 64 + d)) * SEQ + s) = o;
      } else {
#pragma unroll
        for (int j = 0; j < 4; ++j) {
          int row = mt * 128 + wr * 64 + mi * 16 + (lane >> 4) * 4 + j;
          float v = (acc[mi][ni][j] + bv) * scale;
          if constexpr (MODE == 0) {
            C[(size_t)row * DM + col] = __float2bfloat16(v);
          } else {
            C[(size_t)row * DM + col] = v;
          }
        }
      }
    }
  }
}

// Q prescale: (1/sqrt(64)) * log2(e) so attention uses exp2
static constexpr float QSCALE = 0.125f * 1.4426950408889634f;

__global__ __launch_bounds__(256) void qkv_gemm(const bf16* __restrict__ aib,
                                                const bf16* __restrict__ xb,
                                                const bf16* __restrict__ wqt,
                                                const bf16* __restrict__ wkt,
                                                const bf16* __restrict__ wvt,
                                                const float* __restrict__ bq,
                                                const float* __restrict__ bk,
                                                const float* __restrict__ bv,
                                                bf16* __restrict__ Q, bf16* __restrict__ K,
                                                bf16* __restrict__ Vt) {
  int mt = blockIdx.x & 31;
  int nt = (blockIdx.x >> 5) & 7;
  int mat = blockIdx.x >> 8;
  if (mat == 0) {
    gemm128_body<0>(aib, wqt, bq, Q, mt, nt, QSCALE);
  } else if (mat == 1) {
    gemm128_body<0>(aib, wkt, bk, K, mt, nt, 1.0f);
  } else {
    gemm128_body<2>(xb, wvt, bv, Vt, mt, nt, 1.0f);
  }
}

__global__ __launch_bounds__(256) void o_gemm(const bf16* __restrict__ Z,
                                              const bf16* __restrict__ wot,
                                              const float* __restrict__ bo,
                                              float* __restrict__ out) {
  int mt = blockIdx.x & 31;
  int nt = blockIdx.x >> 5;
  gemm128_body<1>(Z, wot, bo, out, mt, nt, 1.0f);
}

// ---------------- flash attention: swapped-QK^T, 1 wave / 32 q-rows ----------
// S^T = mfma32x32x16(K,Q): lane owns full q-row (q=lane&31). K AND V double-
// buffered in registers: t+1 loads issued right after QK^T MFMAs -> full-tile
// latency cover. Defer-max skips rescale when running max unchanged (exact).
__global__ __launch_bounds__(64, 2) void flash_attn(const bf16* __restrict__ Qb,
                                                    const bf16* __restrict__ Kb,
                                                    const bf16* __restrict__ Vt,
                                                    bf16* __restrict__ Zb) {
  __shared__ unsigned Zl[32 * 32];  // 4KB, final ZT->Z transpose

  const int lane = threadIdx.x;
  const int qln = lane & 31;
  const int hi8 = (lane >> 5) * 8;
  const bool hib = lane >= 32;
  const int bh = blockIdx.x & 31;           // bh%8 == blockIdx%8 -> XCD affinity
  const int wq = 63 - (blockIdx.x >> 5);    // heavy blocks dispatch first
  const int bb = bh >> 4, h = bh & 15;
  const size_t base = ((size_t)bb * SEQ) * DM + h * DHD;
  const size_t vbase = (size_t)bh * DHD * SEQ;
  const int q0 = wq * 32;
  const int ntiles = wq / 2 + 1;

  // Q fragments (B operand): row q = q0+qln, k = kc*16 + hi8 + e
  short8 qf[4];
#pragma unroll
  for (int kc = 0; kc < 4; ++kc)
    qf[kc] = *(const short8*)(Qb + base + (size_t)(q0 + qln) * DM + kc * 16 + hi8);

  f32x16 zacc[2];
#pragma unroll
  for (int i = 0; i < 16; ++i) { zacc[0][i] = 0.f; zacc[1][i] = 0.f; }
  float mrun = -1e30f, lrun = 0.f;

  auto loadK = [&](short8(&kf)[2][4], int tt) {
#pragma unroll
    for (int ni = 0; ni < 2; ++ni)
#pragma unroll
      for (int kc = 0; kc < 4; ++kc)
        kf[ni][kc] = *(const short8*)(Kb + base + (size_t)(tt * 64 + 32 * ni + qln) * DM + kc * 16 + hi8);
  };
  auto loadV = [&](short8(&vf)[2][4], int tt) {
#pragma unroll
    for (int dj = 0; dj < 2; ++dj)
#pragma unroll
      for (int c = 0; c < 4; ++c)
        vf[dj][c] = *(const short8*)(Vt + vbase + (size_t)(32 * dj + qln) * SEQ + tt * 64 + c * 16 + hi8);
  };

  auto computeT = [&](short8(&kf)[2][4], short8(&kfn)[2][4],
                      short8(&vf)[2][4], short8(&vfn)[2][4], int t) {
    const int kv0 = t * 64;
    const bool pref = (t + 1 < ntiles);

    // S^T[kv][q]
    f32x16 s[2];
#pragma unroll
    for (int i = 0; i < 16; ++i) { s[0][i] = 0.f; s[1][i] = 0.f; }
#pragma unroll
    for (int kc = 0; kc < 4; ++kc) {
      s[0] = __builtin_amdgcn_mfma_f32_32x32x16_bf16(kf[0][kc], qf[kc], s[0], 0, 0, 0);
      s[1] = __builtin_amdgcn_mfma_f32_32x32x16_bf16(kf[1][kc], qf[kc], s[1], 0, 0, 0);
    }

    if (pref) {           // issue next tile's K AND V under the softmax
      loadK(kfn, t + 1);
      loadV(vfn, t + 1);
    }

    if (t == ntiles - 1) {  // causal mask, only diagonal tile
      const int qg = q0 + qln;
#pragma unroll
      for (int ni = 0; ni < 2; ++ni)
#pragma unroll
        for (int rr = 0; rr < 16; ++rr) {
          int kv = kv0 + 32 * ni + (rr & 3) + 8 * (rr >> 2) + (hib ? 4 : 0);
          if (kv > qg) s[ni][rr] = -1e30f;
        }
    }

    // row max: in-register tree + 1 cross-half shuffle
    float t8[8];
#pragma unroll
    for (int i = 0; i < 8; ++i)
      t8[i] = fmaxf(fmaxf(s[0][i], s[0][i + 8]), fmaxf(s[1][i], s[1][i + 8]));
    float tm = fmaxf(fmaxf(fmaxf(t8[0], t8[1]), fmaxf(t8[2], t8[3])),
                     fmaxf(fmaxf(t8[4], t8[5]), fmaxf(t8[6], t8[7])));
    tm = fmaxf(tm, __shfl_xor(tm, 32));

    // defer-max: rescale only if the running max actually grew (exact)
    if (__ballot(tm > mrun)) {
      float mn = fmaxf(mrun, tm);
      float al = exp2f(mrun - mn);
      mrun = mn;
      lrun *= al;
#pragma unroll
      for (int i = 0; i < 16; ++i) { zacc[0][i] *= al; zacc[1][i] *= al; }
    }

    float pacc[4] = {0.f, 0.f, 0.f, 0.f};
#pragma unroll
    for (int ni = 0; ni < 2; ++ni)
#pragma unroll
      for (int rr = 0; rr < 16; ++rr) {
        float p = exp2f(s[ni][rr] - mrun);
        s[ni][rr] = p;
        pacc[rr & 3] += p;
      }
    float sum = (pacc[0] + pacc[1]) + (pacc[2] + pacc[3]);
    sum += __shfl_xor(sum, 32);
    lrun += sum;

    // P -> bf16 A-fragments: packed cvt, swap halves, select
    unsigned su32[2][8], X[2][8];
#pragma unroll
    for (int ni = 0; ni < 2; ++ni)
#pragma unroll
      for (int tt = 0; tt < 8; ++tt)
        su32[ni][tt] = pack2(s[ni][2 * tt], s[ni][2 * tt + 1]);
#pragma unroll
    for (int ni = 0; ni < 2; ++ni)
#pragma unroll
      for (int tt = 0; tt < 8; ++tt)
        X[ni][tt] = (unsigned)__shfl_xor((int)su32[ni][tt], 32);

    short8 pa[4];
#pragma unroll
    for (int c = 0; c < 4; ++c) {
      int ni = c >> 1, b4 = 4 * (c & 1);
      U8 w;
      w.u[0] = hib ? X[ni][b4 + 0] : su32[ni][b4 + 0];
      w.u[1] = hib ? X[ni][b4 + 1] : su32[ni][b4 + 1];
      w.u[2] = hib ? su32[ni][b4 + 2] : X[ni][b4 + 2];
      w.u[3] = hib ? su32[ni][b4 + 3] : X[ni][b4 + 3];
      // correct half-ordering: low half owns regs 0..3 (kv&4==0), high owns 4..7
      w.u[0] = hib ? X[ni][b4 + 2] : su32[ni][b4 + 0];
      w.u[1] = hib ? X[ni][b4 + 3] : su32[ni][b4 + 1];
      w.u[2] = hib ? su32[ni][b4 + 2] : X[ni][b4 + 0];
      w.u[3] = hib ? su32[ni][b4 + 3] : X[ni][b4 + 1];
      pa[c] = w.s;
    }

    // Z^T += V^T * P
#pragma unroll
    for (int c = 0; c < 4; ++c) {
      zacc[0] = __builtin_amdgcn_mfma_f32_32x32x16_bf16(vf[0][c], pa[c], zacc[0], 0, 0, 0);
      zacc[1] = __builtin_amdgcn_mfma_f32_32x32x16_bf16(vf[1][c], pa[c], zacc[1], 0, 0, 0);
    }
  };

  short8 kfA[2][4], kfB[2][4], vfA[2][4], vfB[2][4];
  loadK(kfA, 0);
  loadV(vfA, 0);
  int t = 0;
  while (true) {
    computeT(kfA, kfB, vfA, vfB, t);
    if (++t >= ntiles) break;
    computeT(kfB, kfA, vfB, vfA, t);
    if (++t >= ntiles) break;
  }

  // normalize + transpose Z^T -> Z via swizzled LDS, coalesced store
  const float rl = 1.0f / lrun;
  const int W8[8] = {0, 1, 4, 5, 8, 9, 12, 13};
#pragma unroll
  for (int dj = 0; dj < 2; ++dj)
#pragma unroll
    for (int tt = 0; tt < 8; ++tt) {
      unsigned v = pack2(zacc[dj][2 * tt] * rl, zacc[dj][2 * tt + 1] * rl);
      int x = 16 * dj + (hib ? 2 : 0) + W8[tt];
      Zl[qln * 32 + (((x >> 2) ^ (qln & 7)) << 2) + (x & 3)] = v;
    }
  asm volatile("s_waitcnt lgkmcnt(0)" ::: "memory");
  int q2 = lane >> 1, hf = lane & 1;
#pragma unroll
  for (int u = 0; u < 4; ++u) {
    int sl = (hf * 4 + u) ^ (q2 & 7);
    U8 w;
    w.u = *(const uint4v*)&Zl[q2 * 32 + sl * 4];
    *(short8*)(Zb + base + (size_t)(q0 + q2) * DM + hf * 32 + u * 8) = w.s;
  }
}

extern "C" void kernel_launch(void* const* d_in, const int* in_sizes, int n_in,
                              void* d_out, int out_size, void* d_ws, size_t ws_size,
                              hipStream_t stream) {
  (void)in_sizes; (void)n_in; (void)out_size; (void)ws_size;
  const float* x = (const float*)d_in[0];
  const float* pos = (const float*)d_in[1];
  const float* WQ = (const float*)d_in[2];
  const float* bQ = (const float*)d_in[3];
  const float* WK = (const float*)d_in[4];
  const float* bK = (const float*)d_in[5];
  const float* WV = (const float*)d_in[6];
  const float* bV = (const float*)d_in[7];
  const float* WO = (const float*)d_in[8];
  const float* bO = (const float*)d_in[9];
  float* out = (float*)d_out;

  bf16* ws = (bf16*)d_ws;
  size_t off = 0;
  bf16* aib = ws + off; off += (size_t)MROWS * DM;
  bf16* xb  = ws + off; off += (size_t)MROWS * DM;
  bf16* wqt = ws + off; off += (size_t)DM * DM;
  bf16* wkt = ws + off; off += (size_t)DM * DM;
  bf16* wvt = ws + off; off += (size_t)DM * DM;
  bf16* wot = ws + off; off += (size_t)DM * DM;
  bf16* Qb  = ws + off; off += (size_t)MROWS * DM;
  bf16* Kb  = ws + off; off += (size_t)MROWS * DM;
  bf16* Vtb = ws + off; off += (size_t)MROWS * DM;  // [bh][d][s]
  bf16* Zb  = ws + off; off += (size_t)MROWS * DM;

  prep_inputs<<<(MROWS * DM / 4 + 255) / 256, 256, 0, stream>>>(x, pos, xb, aib);
  dim3 gq(1, 16, 16);
  transpose_w<<<gq, 256, 0, stream>>>(WQ, wqt, 1024, 64);
  transpose_w<<<gq, 256, 0, stream>>>(WK, wkt, 1024, 64);
  transpose_w<<<gq, 256, 0, stream>>>(WV, wvt, 1024, 64);
  dim3 go(16, 16, 1);
  transpose_w<<<go, 256, 0, stream>>>(WO, wot, 1024, 1024);
  qkv_gemm<<<768, 256, 0, stream>>>(aib, xb, wqt, wkt, wvt, bQ, bK, bV, Qb, Kb, Vtb);
  flash_attn<<<2048, 64, 0, stream>>>(Qb, Kb, Vtb, Zb);
  o_gemm<<<256, 256, 0, stream>>>(Zb, wot, bO, out);
}